// Round 2
// baseline (61.679 us; speedup 1.0000x reference)
//
#include <hip/hip_runtime.h>

// ForegroundConsistencyLoss — N=8192 points, C=20 classes.
// loss = sum over pairs(i,j) of max(cos_sim(logits_i,logits_j),0)
//        where both fg (argmax!=0) and dist^2 > 4, divided by pair count.
//
// recs layout (per point, 24 floats): ln[20] (normalized logits), p[3], sq'
// sq' = fg ? |p|^2 : -3e38  -> folds fg mask into the distance test:
//   d2 = sq_i' + sq_j' - 2*dot3 > 4.0 is false whenever either is bg.

#define C_CLS 20
#define RECW  24
#define ROWS_PER_BLOCK 256
#define COLS_PER_BLOCK 128

__global__ void __launch_bounds__(256) fcl_prep(const float* __restrict__ pc,
                                                const float* __restrict__ logits,
                                                float* __restrict__ recs, int n) {
    int i = blockIdx.x * blockDim.x + threadIdx.x;
    if (i >= n) return;
    const float* lg = logits + i * C_CLS;
    float l[C_CLS];
#pragma unroll
    for (int k = 0; k < C_CLS; ++k) l[k] = lg[k];
    // fg: argmax != 0  <=>  max(l[1..C-1]) > l[0]  (ties go to index 0)
    float m = l[1];
#pragma unroll
    for (int k = 2; k < C_CLS; ++k) m = fmaxf(m, l[k]);
    bool fg = m > l[0];
    float ss = 0.f;
#pragma unroll
    for (int k = 0; k < C_CLS; ++k) ss = fmaf(l[k], l[k], ss);
    float inv = 1.0f / fmaxf(sqrtf(ss), 1e-8f);
    float px = pc[i * 3 + 0], py = pc[i * 3 + 1], pz = pc[i * 3 + 2];
    float sq = px * px + py * py + pz * pz;
    float* r = recs + i * RECW;
#pragma unroll
    for (int k = 0; k < C_CLS; ++k) r[k] = l[k] * inv;
    r[20] = px; r[21] = py; r[22] = pz;
    r[23] = fg ? sq : -3.0e38f;
}

__global__ void __launch_bounds__(256) fcl_pairs(const float* __restrict__ recs,
                                                 float* __restrict__ psums,
                                                 int* __restrict__ pcnts) {
    const int i = blockIdx.x * ROWS_PER_BLOCK + threadIdx.x;
    // own record -> registers
    float my[RECW];
#pragma unroll
    for (int k = 0; k < RECW; ++k) my[k] = recs[i * RECW + k];

    float psum = 0.f;
    int cnt = 0;
    const int j0 = blockIdx.y * COLS_PER_BLOCK;
#pragma unroll 2
    for (int j = j0; j < j0 + COLS_PER_BLOCK; ++j) {
        const float* __restrict__ rj = recs + j * RECW;  // block-uniform address
        float d0 = 0.f, d1 = 0.f;
#pragma unroll
        for (int k = 0; k < C_CLS; k += 2) {
            d0 = fmaf(my[k], rj[k], d0);
            d1 = fmaf(my[k + 1], rj[k + 1], d1);
        }
        float dotc = d0 + d1;
        float dot3 = fmaf(my[20], rj[20], fmaf(my[21], rj[21], my[22] * rj[22]));
        float d2 = my[23] + rj[23] - 2.0f * dot3;
        bool cond = d2 > 4.0f;
        psum += cond ? fmaxf(dotc, 0.f) : 0.f;
        cnt += cond ? 1 : 0;
    }

    // wave reduce (64 lanes)
#pragma unroll
    for (int off = 32; off > 0; off >>= 1) {
        psum += __shfl_down(psum, off);
        cnt  += __shfl_down(cnt, off);
    }
    __shared__ float sps[4];
    __shared__ int   scs[4];
    int wid = threadIdx.x >> 6, lane = threadIdx.x & 63;
    if (lane == 0) { sps[wid] = psum; scs[wid] = cnt; }
    __syncthreads();
    if (threadIdx.x == 0) {
        float s = sps[0] + sps[1] + sps[2] + sps[3];
        int   c = scs[0] + scs[1] + scs[2] + scs[3];
        int bid = blockIdx.y * gridDim.x + blockIdx.x;
        psums[bid] = s;
        pcnts[bid] = c;
    }
}

__global__ void __launch_bounds__(256) fcl_final(const float* __restrict__ psums,
                                                 const int* __restrict__ pcnts,
                                                 float* __restrict__ out, int nb) {
    float s = 0.f;
    int c = 0;
    for (int k = threadIdx.x; k < nb; k += 256) { s += psums[k]; c += pcnts[k]; }
#pragma unroll
    for (int off = 32; off > 0; off >>= 1) {
        s += __shfl_down(s, off);
        c += __shfl_down(c, off);
    }
    __shared__ float sps[4];
    __shared__ int   scs[4];
    int wid = threadIdx.x >> 6, lane = threadIdx.x & 63;
    if (lane == 0) { sps[wid] = s; scs[wid] = c; }
    __syncthreads();
    if (threadIdx.x == 0) {
        float ts = sps[0] + sps[1] + sps[2] + sps[3];
        int   tc = scs[0] + scs[1] + scs[2] + scs[3];
        out[0] = (tc > 0) ? ts / (float)tc : 1.0f;
    }
}

extern "C" void kernel_launch(void* const* d_in, const int* in_sizes, int n_in,
                              void* d_out, int out_size, void* d_ws, size_t ws_size,
                              hipStream_t stream) {
    const float* pc     = (const float*)d_in[0];  // [N,3]
    const float* logits = (const float*)d_in[1];  // [N,20]
    float* out = (float*)d_out;

    const int N = in_sizes[0] / 3;                // 8192
    float* recs  = (float*)d_ws;                              // N*RECW floats
    float* psums = (float*)((char*)d_ws + (size_t)N * RECW * sizeof(float));
    const int nrb = N / ROWS_PER_BLOCK;                       // 32
    const int ncb = N / COLS_PER_BLOCK;                       // 64
    const int nb  = nrb * ncb;                                // 2048
    int*   pcnts = (int*)(psums + nb);

    fcl_prep<<<(N + 255) / 256, 256, 0, stream>>>(pc, logits, recs, N);
    fcl_pairs<<<dim3(nrb, ncb), 256, 0, stream>>>(recs, psums, pcnts);
    fcl_final<<<1, 256, 0, stream>>>(psums, pcnts, out, nb);
}

// Round 8
// 30.946 us; speedup vs baseline: 1.9931x; 1.9931x over previous
//
#include <hip/hip_runtime.h>

// ForegroundConsistencyLoss — N=8192, C=20.
// loss = mean over pairs {both fg, d2>4} of relu(cos_sim(logits_i, logits_j)).
//
// MFMA formulation: sim = LN·LN^T (K=20 pad 32, bf16), and
// d2 = A'·B' with A'=[-2x,-2y,-2z,sq',1], B'=[x,y,z,1,sq'] (K=5 pad 16),
// sq' = fg ? |p|^2 : -1e30 (sentinel folds fg mask into the d2>4 test).
// Both accs come from v_mfma_f32_32x32x16_bf16 -> identical C/D layout, so
// element-wise (sim, d2) pairing is consistent by construction; the masked
// sum over symmetric matrices is also transpose-invariant. A/B share a
// (lane,e)->k convention, so the true HW k-permutation cancels between
// operands (dot products invariant under common k-permutation).

#define C_CLS 20

typedef __attribute__((ext_vector_type(8)))  short bh8;    // 8 bf16 (4 VGPRs)
typedef __attribute__((ext_vector_type(16))) float fx16;   // 16 f32 acc

// float -> bf16 bits, round-nearest-even (avoids hip_bf16 header member drift)
static __device__ __forceinline__ short f2bf(float x) {
    unsigned u = __float_as_uint(x);
    unsigned r = (u + 0x7fffu + ((u >> 16) & 1u)) >> 16;
    return (short)r;
}

// fragment buffers (shorts):
//  fragS : [256 rowgroups][2 kchunks][64 lanes][8]  = 262144 shorts (512 KB)
//  fragDA: [256][64][8]                             = 131072 shorts (256 KB)
//  fragDB: [256][64][8]                             = 131072 shorts (256 KB)

__global__ void __launch_bounds__(256) fcl_prep(const float* __restrict__ pc,
                                                const float* __restrict__ logits,
                                                short* __restrict__ fragS,
                                                short* __restrict__ fragDA,
                                                short* __restrict__ fragDB, int n) {
    int i = blockIdx.x * blockDim.x + threadIdx.x;
    if (i >= n) return;
    const float* lg = logits + i * C_CLS;
    float l[C_CLS];
#pragma unroll
    for (int k = 0; k < C_CLS; ++k) l[k] = lg[k];
    float m = l[1];
#pragma unroll
    for (int k = 2; k < C_CLS; ++k) m = fmaxf(m, l[k]);
    bool fg = m > l[0];                 // argmax != 0 (ties -> index 0 -> bg)
    float ss = 0.f;
#pragma unroll
    for (int k = 0; k < C_CLS; ++k) ss = fmaf(l[k], l[k], ss);
    float inv = 1.0f / fmaxf(sqrtf(ss), 1e-8f);
    float px = pc[i * 3 + 0], py = pc[i * 3 + 1], pz = pc[i * 3 + 2];
    float sq = px * px + py * py + pz * pz;
    float sqp = fg ? sq : -1.0e30f;

    int g = i >> 5, r = i & 31;
    // sim operand: rows of LN, K=32 (k>=20 zero)
    short* s0a = fragS + (((g * 2 + 0) * 64 + r) * 8);        // k 0..7
    short* s0b = fragS + (((g * 2 + 0) * 64 + r + 32) * 8);   // k 8..15
    short* s1a = fragS + (((g * 2 + 1) * 64 + r) * 8);        // k 16..23
    short* s1b = fragS + (((g * 2 + 1) * 64 + r + 32) * 8);   // k 24..31
#pragma unroll
    for (int e = 0; e < 8; ++e) {
        s0a[e] = f2bf(l[e] * inv);
        s0b[e] = f2bf(l[8 + e] * inv);
        s1a[e] = (e < 4) ? f2bf(l[16 + e] * inv) : (short)0;
        s1b[e] = (short)0;
    }
    // distance operands (K=16, k>=8 zero)
    short* daa = fragDA + ((g * 64 + r) * 8);
    short* dab = fragDA + ((g * 64 + r + 32) * 8);
    short* dba = fragDB + ((g * 64 + r) * 8);
    short* dbb = fragDB + ((g * 64 + r + 32) * 8);
    daa[0] = f2bf(-2.0f * px); daa[1] = f2bf(-2.0f * py); daa[2] = f2bf(-2.0f * pz);
    daa[3] = f2bf(sqp);        daa[4] = f2bf(1.0f);
    daa[5] = 0; daa[6] = 0; daa[7] = 0;
    dba[0] = f2bf(px); dba[1] = f2bf(py); dba[2] = f2bf(pz);
    dba[3] = f2bf(1.0f); dba[4] = f2bf(sqp);
    dba[5] = 0; dba[6] = 0; dba[7] = 0;
#pragma unroll
    for (int e = 0; e < 8; ++e) { dab[e] = 0; dbb[e] = 0; }
}

__global__ void __launch_bounds__(256) fcl_pairs(const short* __restrict__ fragS,
                                                 const short* __restrict__ fragDA,
                                                 const short* __restrict__ fragDB,
                                                 float* __restrict__ psums,
                                                 int* __restrict__ pcnts) {
    const int tid = threadIdx.x;
    const int lane = tid & 63;
    const int w = blockIdx.x * 4 + (tid >> 6);   // 0..4095
    const int rg = w & 255;                       // row-group (32 rows)
    const int cgb = (w >> 8) << 4;                // 16 col-groups per wave

    const bh8* fS  = (const bh8*)fragS;
    const bh8* fDA = (const bh8*)fragDA;
    const bh8* fDB = (const bh8*)fragDB;

    bh8 aS0 = fS[(rg * 2 + 0) * 64 + lane];
    bh8 aS1 = fS[(rg * 2 + 1) * 64 + lane];
    bh8 aD  = fDA[rg * 64 + lane];

    float psum = 0.f;
    int cnt = 0;
#pragma unroll 2
    for (int t = 0; t < 16; ++t) {
        int cg = cgb + t;
        bh8 bS0 = fS[(cg * 2 + 0) * 64 + lane];
        bh8 bS1 = fS[(cg * 2 + 1) * 64 + lane];
        bh8 bD  = fDB[cg * 64 + lane];
        fx16 accS = {0.f};
        accS = __builtin_amdgcn_mfma_f32_32x32x16_bf16(aS0, bS0, accS, 0, 0, 0);
        accS = __builtin_amdgcn_mfma_f32_32x32x16_bf16(aS1, bS1, accS, 0, 0, 0);
        fx16 accD = {0.f};
        accD = __builtin_amdgcn_mfma_f32_32x32x16_bf16(aD, bD, accD, 0, 0, 0);
#pragma unroll
        for (int r2 = 0; r2 < 16; ++r2) {
            bool c = accD[r2] > 4.0f;
            psum += c ? fmaxf(accS[r2], 0.f) : 0.f;
            cnt  += c ? 1 : 0;
        }
    }

    // wave reduce (64 lanes)
#pragma unroll
    for (int off = 32; off > 0; off >>= 1) {
        psum += __shfl_down(psum, off);
        cnt  += __shfl_down(cnt, off);
    }
    __shared__ float sps[4];
    __shared__ int   scs[4];
    int wid = tid >> 6;
    if ((tid & 63) == 0) { sps[wid] = psum; scs[wid] = cnt; }
    __syncthreads();
    if (tid == 0) {
        psums[blockIdx.x] = sps[0] + sps[1] + sps[2] + sps[3];
        pcnts[blockIdx.x] = scs[0] + scs[1] + scs[2] + scs[3];
    }
}

__global__ void __launch_bounds__(256) fcl_final(const float* __restrict__ psums,
                                                 const int* __restrict__ pcnts,
                                                 float* __restrict__ out, int nb) {
    float s = 0.f;
    int c = 0;
    for (int k = threadIdx.x; k < nb; k += 256) { s += psums[k]; c += pcnts[k]; }
#pragma unroll
    for (int off = 32; off > 0; off >>= 1) {
        s += __shfl_down(s, off);
        c += __shfl_down(c, off);
    }
    __shared__ float sps[4];
    __shared__ int   scs[4];
    int wid = threadIdx.x >> 6, lane = threadIdx.x & 63;
    if (lane == 0) { sps[wid] = s; scs[wid] = c; }
    __syncthreads();
    if (threadIdx.x == 0) {
        float ts = sps[0] + sps[1] + sps[2] + sps[3];
        int   tc = scs[0] + scs[1] + scs[2] + scs[3];
        out[0] = (tc > 0) ? ts / (float)tc : 1.0f;
    }
}

extern "C" void kernel_launch(void* const* d_in, const int* in_sizes, int n_in,
                              void* d_out, int out_size, void* d_ws, size_t ws_size,
                              hipStream_t stream) {
    const float* pc     = (const float*)d_in[0];  // [N,3]
    const float* logits = (const float*)d_in[1];  // [N,20]
    float* out = (float*)d_out;

    const int N = in_sizes[0] / 3;  // 8192
    // ws layout (shorts for fragments)
    short* fragS  = (short*)d_ws;                       // 262144 shorts
    short* fragDA = fragS + 262144;                     // 131072 shorts
    short* fragDB = fragDA + 131072;                    // 131072 shorts
    float* psums  = (float*)(fragDB + 131072);          // 1024 floats
    int*   pcnts  = (int*)(psums + 1024);               // 1024 ints

    const int nblocks = 1024;  // 4 waves each -> 4096 waves -> 16 tiles/wave

    fcl_prep<<<(N + 255) / 256, 256, 0, stream>>>(pc, logits, fragS, fragDA, fragDB, N);
    fcl_pairs<<<nblocks, 256, 0, stream>>>(fragS, fragDA, fragDB, psums, pcnts);
    fcl_final<<<1, 256, 0, stream>>>(psums, pcnts, out, nblocks);
}